// Round 2
// baseline (172231.445 us; speedup 1.0000x reference)
//
#include <hip/hip_runtime.h>
#include <stdint.h>

typedef __attribute__((ext_vector_type(8))) short short8;
typedef __attribute__((ext_vector_type(4))) float f32x4;

#define DEV __device__ __forceinline__

#define L2E 1.4426950408889634f

DEV unsigned short f2bf(float f) {
    union { float f; uint32_t u; } v; v.f = f;
    return (unsigned short)((v.u + 0x7FFFu + ((v.u >> 16) & 1u)) >> 16);
}
DEV float bf2f(unsigned short b) {
    union { uint32_t u; float f; } v; v.u = ((uint32_t)b) << 16;
    return v.f;
}
DEV float sig_(float x) {
    return __builtin_amdgcn_rcpf(1.f + __builtin_amdgcn_exp2f(-L2E * x));
}
DEV float tanh_(float x) {
    // tanh(x) = 1 - 2/(e^{2x}+1); exp2 overflow/underflow saturates correctly
    return 1.f - 2.f * __builtin_amdgcn_rcpf(1.f + __builtin_amdgcn_exp2f(2.f * L2E * x));
}
DEV float elu_(float x) {
    return x > 0.f ? x : __builtin_amdgcn_exp2f(L2E * x) - 1.f;
}
DEV f32x4 splat4(float v) { f32x4 r; r[0]=v; r[1]=v; r[2]=v; r[3]=v; return r; }

// ---------------------------------------------------------------------------
// pack fp32 weights -> bf16 in MFMA B-operand layout [G*NG rows (n)][Kd cols (k)]
// row n: gate g = n/NG, jj = n%NG ; value = src[(g*Hs+jj)*Ks + k] if jj<Hs && k<Ks else 0
// ---------------------------------------------------------------------------
__global__ void pack_kernel(const float* __restrict__ src, unsigned short* __restrict__ dst,
                            int Hs, int NG, int Ks, int Kd, int total)
{
    int e = blockIdx.x * 256 + threadIdx.x;
    if (e >= total) return;
    int n = e / Kd, k = e - n * Kd;
    int g = n / NG, jj = n - g * NG;
    float v = (jj < Hs && k < Ks) ? src[((size_t)(g * Hs + jj)) * Ks + k] : 0.f;
    dst[e] = f2bf(v);
}

// ---------------------------------------------------------------------------
// Fused encoder + GRU recurrence. One block = 32 batch rows, all 512 steps.
// Per step: gather 32 points (idx[t] is batch-uniform; prefetched 2 steps
// ahead), layer1 on VALU, layer2 via MFMA -> x_t in LDS, then GRU step with
// bf16 h (ping-pong LDS) + fp32 hreg in registers. Weights stream from L2.
// Work split: NCT*2 (ct,rt) 16x16 tiles spread evenly over 8 waves (PW each).
// H=187 -> KP=192 zero-padded; pad columns are self-consistently zero.
// LDS layout (fixed at prox sizes, total 46592 B):
//   0      hlds [2][32][KP+8] bf16   (prox: 25600 B)
//   25600  xs   [32][72] bf16        (4608 B)
//   30208  h1s  [32][72] bf16        (4608 B)
//   34816  w2s  [64][72] bf16        (9216 B)
//   44032  pts  [2][32][4] f32       (1024 B)
//   45056  w1s  [64][4] f32          (1024 B)
//   46080  b1s  [64] f32             (256 B)
//   46336  b2s  [64] f32             (256 B)
// ---------------------------------------------------------------------------
template<int H, int KP, int PW>
DEV void gru_body(int blk,
                  const float* __restrict__ obs, const int* __restrict__ idx,
                  const float* __restrict__ w1, const float* __restrict__ b1,
                  const float* __restrict__ w2, const float* __restrict__ b2,
                  const unsigned short* __restrict__ wih, const unsigned short* __restrict__ whh,
                  const float* __restrict__ bih, const float* __restrict__ bhh,
                  float* __restrict__ hout, char* smem)
{
    constexpr int NCT = KP / 16;            // col tiles per gate
    constexpr int KS  = KP / 32;            // k-steps for gh
    constexpr int HP8 = KP + 8;             // padded h row (shorts)
    constexpr int NDC = (PW == 3) ? 2 : 1;  // distinct cts per wave

    unsigned short* hlds = (unsigned short*)(smem);
    unsigned short* xs   = (unsigned short*)(smem + 25600);
    unsigned short* h1s  = (unsigned short*)(smem + 30208);
    unsigned short* w2s  = (unsigned short*)(smem + 34816);
    float* ptsb          = (float*)(smem + 44032);
    float* w1s           = (float*)(smem + 45056);
    float* b1s           = (float*)(smem + 46080);
    float* b2s           = (float*)(smem + 46336);

    const int tid  = threadIdx.x;
    const int wave = tid >> 6, lane = tid & 63, quad = lane >> 4, l16 = lane & 15;
    const int b0   = blk * 32;
    const int pb   = wave * PW;
    const int dct0 = pb >> 1;

    // ---- one-time staging ----
    for (int e = tid; e < 2*32*HP8; e += 512) hlds[e] = 0;
    for (int e = tid; e < 4096; e += 512) { int n = e >> 6, k = e & 63; w2s[n*72 + k] = f2bf(w2[e]); }
    for (int e = tid; e < 192; e += 512)  w1s[(e/3)*4 + (e - (e/3)*3)] = w1[e];
    if (tid < 64) { b1s[tid] = b1[tid]; b2s[tid] = b2[tid]; }

    const float* myrow = obs + (size_t)(b0 + (tid & 31)) * 3120 + 48;
    float px = 0.f, py = 0.f, pz = 0.f;
    if (tid < 32) {
        int p0 = idx[0];
        ptsb[tid*4 + 0] = myrow[3*p0 + 0];
        ptsb[tid*4 + 1] = myrow[3*p0 + 1];
        ptsb[tid*4 + 2] = myrow[3*p0 + 2];
        int p1 = idx[1];
        px = myrow[3*p1 + 0]; py = myrow[3*p1 + 1]; pz = myrow[3*p1 + 2];
    }

    // ---- per-pair biases (folded into acc init) ----
    float bsr[PW], bsz[PW], binx[PW], bhnn[PW];
#pragma unroll
    for (int i = 0; i < PW; ++i) {
        int ct = (pb + i) >> 1, c = ct*16 + l16;
        bsr[i] = bsz[i] = binx[i] = bhnn[i] = 0.f;
        if (c < H) {
            bsr[i]  = bih[c]       + bhh[c];
            bsz[i]  = bih[H + c]   + bhh[H + c];
            binx[i] = bih[2*H + c];
            bhnn[i] = bhh[2*H + c];
        }
    }
    float hreg[PW][4];
#pragma unroll
    for (int i = 0; i < PW; ++i)
#pragma unroll
        for (int j = 0; j < 4; ++j) hreg[i][j] = 0.f;

    __syncthreads();

    int cur = 0;
    for (int t = 0; t < 512; ++t) {
        // ---- encoder layer 1 (VALU) ----
        const float* pt = ptsb + (t & 1) * 128;
#pragma unroll
        for (int k2 = 0; k2 < 4; ++k2) {
            int e = tid + k2*512;
            int p = e >> 6, ch = e & 63;
            float v = w1s[ch*4+0]*pt[p*4+0] + w1s[ch*4+1]*pt[p*4+1]
                    + w1s[ch*4+2]*pt[p*4+2] + b1s[ch];
            h1s[p*72 + ch] = f2bf(elu_(v));
        }
        __syncthreads();                               // h1s ready

        // ---- pts store for t+1 + prefetch t+2 (wave 0 only) ----
        if (tid < 32) {
            float* dst = ptsb + ((t+1) & 1) * 128 + tid*4;
            dst[0] = px; dst[1] = py; dst[2] = pz;
            int tn = (t + 2 < 512) ? t + 2 : 511;
            int pn = idx[tn];
            px = myrow[3*pn + 0]; py = myrow[3*pn + 1]; pz = myrow[3*pn + 2];
        }

        // ---- encoder layer 2 (MFMA, 8 waves = 4 ct x 2 rt) ----
        {
            int ct2 = wave & 3, rt2 = wave >> 2;
            f32x4 a2 = splat4(0.f);
#pragma unroll
            for (int ks = 0; ks < 2; ++ks) {
                short8 af = *(const short8*)(h1s + (rt2*16 + l16)*72 + ks*32 + quad*8);
                short8 bf = *(const short8*)(w2s + (ct2*16 + l16)*72 + ks*32 + quad*8);
                a2 = __builtin_amdgcn_mfma_f32_16x16x32_bf16(af, bf, a2, 0, 0, 0);
            }
            int c2 = ct2*16 + l16;
            float b2v = b2s[c2];
#pragma unroll
            for (int j = 0; j < 4; ++j) {
                int m = rt2*16 + quad*4 + j;
                xs[m*72 + c2] = f2bf(elu_(a2[j] + b2v));
            }
        }
        __syncthreads();                               // xs ready

        const unsigned short* hc = hlds + cur * (32*HP8);
        unsigned short*       hn = hlds + (cur ^ 1) * (32*HP8);

        f32x4 acc[PW][4];                              // r, z, nx, nh
#pragma unroll
        for (int i = 0; i < PW; ++i) {
            acc[i][0] = splat4(bsr[i]);
            acc[i][1] = splat4(bsz[i]);
            acc[i][2] = splat4(binx[i]);
            acc[i][3] = splat4(bhnn[i]);
        }

        // ---- gx = x_t @ wih^T (K=64) ----
#pragma unroll
        for (int ks = 0; ks < 2; ++ks) {
            short8 xf[2];
            xf[0] = *(const short8*)(xs + l16*72        + ks*32 + quad*8);
            xf[1] = *(const short8*)(xs + (16+l16)*72   + ks*32 + quad*8);
            short8 bw[NDC][3];
#pragma unroll
            for (int dc = 0; dc < NDC; ++dc)
#pragma unroll
                for (int g = 0; g < 3; ++g)
                    bw[dc][g] = *(const short8*)(wih +
                        ((size_t)(g*KP + (dct0+dc)*16 + l16))*64 + ks*32 + quad*8);
#pragma unroll
            for (int i = 0; i < PW; ++i) {
                int pair = pb + i, rt = pair & 1, dc = (pair >> 1) - dct0;
#pragma unroll
                for (int g = 0; g < 3; ++g)
                    acc[i][g] = __builtin_amdgcn_mfma_f32_16x16x32_bf16(xf[rt], bw[dc][g], acc[i][g], 0, 0, 0);
            }
        }
        // ---- gh = h @ whh^T (K=KP) ----
#pragma unroll
        for (int ks = 0; ks < KS; ++ks) {
            short8 ah[2];
            ah[0] = *(const short8*)(hc + l16*HP8      + ks*32 + quad*8);
            ah[1] = *(const short8*)(hc + (16+l16)*HP8 + ks*32 + quad*8);
            short8 bw[NDC][3];
#pragma unroll
            for (int dc = 0; dc < NDC; ++dc)
#pragma unroll
                for (int g = 0; g < 3; ++g)
                    bw[dc][g] = *(const short8*)(whh +
                        ((size_t)(g*KP + (dct0+dc)*16 + l16))*KP + ks*32 + quad*8);
#pragma unroll
            for (int i = 0; i < PW; ++i) {
                int pair = pb + i, rt = pair & 1, dc = (pair >> 1) - dct0;
#pragma unroll
                for (int g = 0; g < 3; ++g) {
                    int gi = (g == 2) ? 3 : g;
                    acc[i][gi] = __builtin_amdgcn_mfma_f32_16x16x32_bf16(ah[rt], bw[dc][g], acc[i][gi], 0, 0, 0);
                }
            }
        }
        // ---- gates + h update ----
#pragma unroll
        for (int i = 0; i < PW; ++i) {
            int pair = pb + i, ct = pair >> 1, rt = pair & 1, c = ct*16 + l16;
#pragma unroll
            for (int j = 0; j < 4; ++j) {
                int m = rt*16 + quad*4 + j;
                float r  = sig_(acc[i][0][j]);
                float zg = sig_(acc[i][1][j]);
                float nn = tanh_(acc[i][2][j] + r * acc[i][3][j]);
                float hv = nn + zg * (hreg[i][j] - nn);
                hreg[i][j] = hv;
                hn[m*HP8 + c] = f2bf(hv);
            }
        }
        cur ^= 1;
        __syncthreads();                               // hn visible; xs/h1s free
    }

    // ---- final h (exact fp32 from registers) ----
#pragma unroll
    for (int i = 0; i < PW; ++i) {
        int pair = pb + i, ct = pair >> 1, rt = pair & 1, c = ct*16 + l16;
        if (c < H)
#pragma unroll
            for (int j = 0; j < 4; ++j) {
                int m = rt*16 + quad*4 + j;
                hout[(size_t)(b0 + m)*H + c] = hreg[i][j];
            }
    }
}

__global__ __launch_bounds__(512, 2) void gru_kernel(
    const float* __restrict__ obs,
    const int* __restrict__ prox_idx, const int* __restrict__ dist_idx,
    const float* __restrict__ w1p, const float* __restrict__ b1p,
    const float* __restrict__ w2p, const float* __restrict__ b2p,
    const float* __restrict__ w1d, const float* __restrict__ b1d,
    const float* __restrict__ w2d, const float* __restrict__ b2d,
    const unsigned short* __restrict__ wihp, const unsigned short* __restrict__ whhp,
    const unsigned short* __restrict__ wihd, const unsigned short* __restrict__ whhd,
    const float* __restrict__ bihp, const float* __restrict__ bhhp,
    const float* __restrict__ bihd, const float* __restrict__ bhhd,
    float* __restrict__ hp, float* __restrict__ hd)
{
    __shared__ char smem[46592];
    if (blockIdx.x < 64)
        gru_body<187, 192, 3>(blockIdx.x, obs, prox_idx, w1p, b1p, w2p, b2p,
                              wihp, whhp, bihp, bhhp, hp, smem);
    else
        gru_body<64, 64, 1>(blockIdx.x - 64, obs, dist_idx, w1d, b1d, w2d, b2d,
                            wihd, whhd, bihd, bhhd, hd, smem);
}

// ---------------------------------------------------------------------------
// mem GRU with T=1 and h0=0: f = (1-z)*n, gh == bhh.  fp32 exact.
// ---------------------------------------------------------------------------
__global__ __launch_bounds__(192) void mem_kernel(
    const float* __restrict__ hp, const float* __restrict__ hd,
    const float* __restrict__ mwp, const float* __restrict__ mbip, const float* __restrict__ mbhp,
    const float* __restrict__ mwd, const float* __restrict__ mbid, const float* __restrict__ mbhd,
    float* __restrict__ fp, float* __restrict__ fd)
{
    const int b = blockIdx.x, z = blockIdx.y;
    const float* h  = z ? hd  : hp;
    const float* W  = z ? mwd : mwp;
    const float* bi = z ? mbid : mbip;
    const float* bh = z ? mbhd : mbhp;
    float* out = z ? fd : fp;
    const int Hh = z ? 64 : 187;
    __shared__ float hrow[192];
    int j = threadIdx.x;
    if (j < Hh) hrow[j] = h[(size_t)b*Hh + j];
    __syncthreads();
    if (j < Hh) {
        float dr = 0.f, dz = 0.f, dn = 0.f;
        for (int k = 0; k < Hh; ++k) {
            float a = hrow[k];
            dr += a * W[(size_t)(0*Hh + j)*Hh + k];
            dz += a * W[(size_t)(1*Hh + j)*Hh + k];
            dn += a * W[(size_t)(2*Hh + j)*Hh + k];
        }
        float r  = sig_(dr + bi[j] + bh[j]);
        float zg = sig_(dz + bi[Hh + j] + bh[Hh + j]);
        float nn = tanh_(dn + bi[2*Hh + j] + r * bh[2*Hh + j]);
        out[(size_t)b*Hh + j] = (1.f - zg) * nn;
    }
}

__global__ void concat_kernel(const float* __restrict__ obs, const float* __restrict__ fp,
                              const float* __restrict__ fd, float* __restrict__ x0)
{
    int i = blockIdx.x * 256 + threadIdx.x;
    if (i >= 2048 * 299) return;
    int b = i / 299, k = i - b * 299;
    float v;
    if (k < 48)       v = obs[(size_t)b*3120 + k];
    else if (k < 235) v = fp[(size_t)b*187 + (k - 48)];
    else              v = fd[(size_t)b*64 + (k - 235)];
    x0[i] = v;
}

// ---------------------------------------------------------------------------
// fp32 GEMM + bias (+ELU):  C[b][n] = act( A[b][:] . W[n][:] + bias[n] )
// 64x64 tile / block, 256 thr, 4x4 micro-tile, K-steps of 16 via LDS.
// ---------------------------------------------------------------------------
__global__ __launch_bounds__(256) void gemm_kernel(
    const float* __restrict__ A, const float* __restrict__ W, const float* __restrict__ bias,
    float* __restrict__ C, int N, int K, int act)
{
    __shared__ float As[16][68];
    __shared__ float Ws[16][68];
    const int tid = threadIdx.x;
    const int n0 = blockIdx.x * 64, b0 = blockIdx.y * 64;
    const int tx = tid & 15, ty = tid >> 4;
    float acc[4][4];
#pragma unroll
    for (int i = 0; i < 4; ++i)
#pragma unroll
        for (int j = 0; j < 4; ++j) acc[i][j] = 0.f;
    const int lrow = tid >> 2, lseg = (tid & 3) * 4;
    for (int k0 = 0; k0 < K; k0 += 16) {
#pragma unroll
        for (int i = 0; i < 4; ++i) {
            int k = k0 + lseg + i;
            As[lseg + i][lrow] = (k < K) ? A[(size_t)(b0 + lrow)*K + k] : 0.f;
            Ws[lseg + i][lrow] = (k < K && (n0 + lrow) < N) ? W[(size_t)(n0 + lrow)*K + k] : 0.f;
        }
        __syncthreads();
#pragma unroll
        for (int kk = 0; kk < 16; ++kk) {
            float a[4], w[4];
#pragma unroll
            for (int i = 0; i < 4; ++i) a[i] = As[kk][ty*4 + i];
#pragma unroll
            for (int i = 0; i < 4; ++i) w[i] = Ws[kk][tx*4 + i];
#pragma unroll
            for (int i = 0; i < 4; ++i)
#pragma unroll
                for (int j = 0; j < 4; ++j) acc[i][j] += a[i] * w[j];
        }
        __syncthreads();
    }
#pragma unroll
    for (int j = 0; j < 4; ++j) {
        int n = n0 + tx*4 + j;
        if (n >= N) continue;
        float bv = bias[n];
#pragma unroll
        for (int i = 0; i < 4; ++i) {
            int b = b0 + ty*4 + i;
            float v = acc[i][j] + bv;
            if (act) v = elu_(v);
            C[(size_t)b*N + n] = v;
        }
    }
}

// ---------------------------------------------------------------------------
extern "C" void kernel_launch(void* const* d_in, const int* in_sizes, int n_in,
                              void* d_out, int out_size, void* d_ws, size_t ws_size,
                              hipStream_t stream)
{
    (void)in_sizes; (void)n_in; (void)out_size; (void)ws_size;
    const float* obs        = (const float*)d_in[0];
    const int*   prox_idx   = (const int*)d_in[1];
    const int*   dist_idx   = (const int*)d_in[2];
    const float* pe_prox_w1 = (const float*)d_in[3];
    const float* pe_prox_b1 = (const float*)d_in[4];
    const float* pe_prox_w2 = (const float*)d_in[5];
    const float* pe_prox_b2 = (const float*)d_in[6];
    const float* pe_dist_w1 = (const float*)d_in[7];
    const float* pe_dist_b1 = (const float*)d_in[8];
    const float* pe_dist_w2 = (const float*)d_in[9];
    const float* pe_dist_b2 = (const float*)d_in[10];
    const float* gp_wih = (const float*)d_in[11];
    const float* gp_whh = (const float*)d_in[12];
    const float* gp_bih = (const float*)d_in[13];
    const float* gp_bhh = (const float*)d_in[14];
    const float* gd_wih = (const float*)d_in[15];
    const float* gd_whh = (const float*)d_in[16];
    const float* gd_bih = (const float*)d_in[17];
    const float* gd_bhh = (const float*)d_in[18];
    const float* mp_wih = (const float*)d_in[19];
    const float* mp_bih = (const float*)d_in[21];
    const float* mp_bhh = (const float*)d_in[22];
    const float* md_wih = (const float*)d_in[23];
    const float* md_bih = (const float*)d_in[25];
    const float* md_bhh = (const float*)d_in[26];
    const float* aw0 = (const float*)d_in[27]; const float* ab0 = (const float*)d_in[28];
    const float* aw1 = (const float*)d_in[29]; const float* ab1 = (const float*)d_in[30];
    const float* aw2 = (const float*)d_in[31]; const float* ab2 = (const float*)d_in[32];
    const float* aw3 = (const float*)d_in[33]; const float* ab3 = (const float*)d_in[34];
    const float* aw4 = (const float*)d_in[35]; const float* ab4 = (const float*)d_in[36];
    float* out = (float*)d_out;

    char* ws = (char*)d_ws;
    size_t off = 0;
    auto alloc = [&](size_t bytes) -> char* {
        char* p = ws + off;
        off = (off + bytes + 255) & ~(size_t)255;
        return p;
    };
    unsigned short* whh_p = (unsigned short*)alloc(576*192*2);
    unsigned short* wih_p = (unsigned short*)alloc(576*64*2);
    unsigned short* whh_d = (unsigned short*)alloc(192*64*2);
    unsigned short* wih_d = (unsigned short*)alloc(192*64*2);
    float* hp = (float*)alloc((size_t)2048*187*4);
    float* hd = (float*)alloc((size_t)2048*64*4);
    float* fp = (float*)alloc((size_t)2048*187*4);
    float* fd = (float*)alloc((size_t)2048*64*4);
    float* x0 = (float*)alloc((size_t)2048*299*4);
    float* a1 = (float*)alloc((size_t)2048*1024*4);
    float* a2 = (float*)alloc((size_t)2048*512*4);
    float* a3 = (float*)alloc((size_t)2048*256*4);
    float* a4 = (float*)alloc((size_t)2048*128*4);
    // total ~22.6 MB of ws

    // --- weight packs (bf16, B-operand layouts) ---
    pack_kernel<<<(36864+255)/256,  256, 0, stream>>>(gp_wih, wih_p, 187, 192, 64, 64, 36864);
    pack_kernel<<<(110592+255)/256, 256, 0, stream>>>(gp_whh, whh_p, 187, 192, 187, 192, 110592);
    pack_kernel<<<(12288+255)/256,  256, 0, stream>>>(gd_wih, wih_d, 64, 64, 64, 64, 12288);
    pack_kernel<<<(12288+255)/256,  256, 0, stream>>>(gd_whh, whh_d, 64, 64, 64, 64, 12288);

    // --- fused encoder + GRU recurrence ---
    gru_kernel<<<128, 512, 0, stream>>>(
        obs, prox_idx, dist_idx,
        pe_prox_w1, pe_prox_b1, pe_prox_w2, pe_prox_b2,
        pe_dist_w1, pe_dist_b1, pe_dist_w2, pe_dist_b2,
        wih_p, whh_p, wih_d, whh_d,
        gp_bih, gp_bhh, gd_bih, gd_bhh, hp, hd);

    // --- mem GRUs (T=1, h0=0) ---
    mem_kernel<<<dim3(2048, 2), 192, 0, stream>>>(
        hp, hd, mp_wih, mp_bih, mp_bhh, md_wih, md_bih, md_bhh, fp, fd);

    // --- concat [proprio | fp | fd] ---
    concat_kernel<<<(2048*299 + 255)/256, 256, 0, stream>>>(obs, fp, fd, x0);

    // --- actor MLP ---
    gemm_kernel<<<dim3(16, 32), 256, 0, stream>>>(x0, aw0, ab0, a1, 1024, 299, 1);
    gemm_kernel<<<dim3(8,  32), 256, 0, stream>>>(a1, aw1, ab1, a2, 512, 1024, 1);
    gemm_kernel<<<dim3(4,  32), 256, 0, stream>>>(a2, aw2, ab2, a3, 256, 512, 1);
    gemm_kernel<<<dim3(2,  32), 256, 0, stream>>>(a3, aw3, ab3, a4, 128, 256, 1);
    gemm_kernel<<<dim3(1,  32), 256, 0, stream>>>(a4, aw4, ab4, out, 12, 128, 0);
}

// Round 3
// 1406.609 us; speedup vs baseline: 122.4444x; 122.4444x over previous
//
#include <hip/hip_runtime.h>
#include <stdint.h>

typedef __attribute__((ext_vector_type(8))) short short8;
typedef __attribute__((ext_vector_type(4))) float f32x4;

#define DEV __device__ __forceinline__

#define L2E 1.4426950408889634f

DEV unsigned short f2bf(float f) {
    union { float f; uint32_t u; } v; v.f = f;
    return (unsigned short)((v.u + 0x7FFFu + ((v.u >> 16) & 1u)) >> 16);
}
DEV float sig_(float x) {
    return __builtin_amdgcn_rcpf(1.f + __builtin_amdgcn_exp2f(-L2E * x));
}
DEV float tanh_(float x) {
    return 1.f - 2.f * __builtin_amdgcn_rcpf(1.f + __builtin_amdgcn_exp2f(2.f * L2E * x));
}
DEV float elu_(float x) {
    return x > 0.f ? x : __builtin_amdgcn_exp2f(L2E * x) - 1.f;
}
DEV f32x4 splat4(float v) { f32x4 r; r[0]=v; r[1]=v; r[2]=v; r[3]=v; return r; }

// ---------------------------------------------------------------------------
// pack fp32 weights -> bf16 in MFMA B-operand layout [G*NG rows (n)][Kd cols (k)]
// ---------------------------------------------------------------------------
__global__ void pack_kernel(const float* __restrict__ src, unsigned short* __restrict__ dst,
                            int Hs, int NG, int Ks, int Kd, int total)
{
    int e = blockIdx.x * 256 + threadIdx.x;
    if (e >= total) return;
    int n = e / Kd, k = e - n * Kd;
    int g = n / NG, jj = n - g * NG;
    float v = (jj < Hs && k < Ks) ? src[((size_t)(g * Hs + jj)) * Ks + k] : 0.f;
    dst[e] = f2bf(v);
}

// ---------------------------------------------------------------------------
// Fused encoder + GRU. One block = 16 batch rows, 768 thr (12 waves), all 512
// steps. Wave w owns column tile ct=w (16 gate-cols, all 3 gates); its whh/wih
// B-fragments live in REGISTERS (loaded once: 72+24 VGPR) -> zero per-step
// weight traffic, no spills (persistent ~120 VGPR, cap 170 via lb(768,3)).
// Per step: gather 16 pts (prefetched 2 ahead) -> l1 VALU -> l2 MFMA (waves
// 0..3) -> x_t in LDS -> gx+gh MFMA from register B-frags -> gates -> bf16 h
// ping-pong in LDS; fp32 h carried in hreg for the z*h term and final output.
// LDS (fixed offsets, prox-max sizes, 28672 B total):
//   0      hlds [2][16][200] bf16 (12800)   17408  w2s [64][72] bf16 (9216)
//   12800  xs   [16][72] bf16    (2304)     26624  pts [2][16][4] f32 (512)
//   15104  h1s  [16][72] bf16    (2304)     27136  w1s [64][4] f32 (1024)
//   28160  b1s[64] f32 ; 28416 b2s[64] f32 ; total 28672
// ---------------------------------------------------------------------------
template<int H, int KP>
DEV void gru_body(int blk,
                  const float* __restrict__ obs, const int* __restrict__ idx,
                  const float* __restrict__ w1, const float* __restrict__ b1,
                  const float* __restrict__ w2, const float* __restrict__ b2,
                  const unsigned short* __restrict__ wih, const unsigned short* __restrict__ whh,
                  const float* __restrict__ bih, const float* __restrict__ bhh,
                  float* __restrict__ hout, char* smem)
{
    constexpr int NCT = KP / 16;            // col tiles (= active waves)
    constexpr int KS  = KP / 32;            // k-steps for gh
    constexpr int HP8 = KP + 8;             // padded h row (shorts)

    unsigned short* hlds = (unsigned short*)(smem);
    unsigned short* xs   = (unsigned short*)(smem + 12800);
    unsigned short* h1s  = (unsigned short*)(smem + 15104);
    unsigned short* w2s  = (unsigned short*)(smem + 17408);
    float* ptsb          = (float*)(smem + 26624);
    float* w1s           = (float*)(smem + 27136);
    float* b1s           = (float*)(smem + 28160);
    float* b2s           = (float*)(smem + 28416);

    const int tid  = threadIdx.x;
    const int wave = tid >> 6, lane = tid & 63, quad = lane >> 4, l16 = lane & 15;
    const int b0   = blk * 16;
    const int ct   = wave;                  // one col tile per wave
    const bool act = (ct < NCT);
    const int c    = ct * 16 + l16;

    // ---- one-time staging ----
    for (int e = tid; e < 2*16*HP8; e += 768) hlds[e] = 0;
    for (int e = tid; e < 4096; e += 768) { int n = e >> 6, k = e & 63; w2s[n*72 + k] = f2bf(w2[e]); }
    if (tid < 192) w1s[(tid/3)*4 + (tid - (tid/3)*3)] = w1[tid];
    if (tid < 64) { b1s[tid] = b1[tid]; b2s[tid] = b2[tid]; }

    const float* myrow = obs + (size_t)(b0 + (tid & 15)) * 3120 + 48;
    float px = 0.f, py = 0.f, pz = 0.f;
    if (tid < 16) {
        int p0 = idx[0];
        ptsb[tid*4 + 0] = myrow[3*p0 + 0];
        ptsb[tid*4 + 1] = myrow[3*p0 + 1];
        ptsb[tid*4 + 2] = myrow[3*p0 + 2];
        int p1 = idx[1];
        px = myrow[3*p1 + 0]; py = myrow[3*p1 + 1]; pz = myrow[3*p1 + 2];
    }

    // ---- register-resident weight fragments (the whole point) ----
    short8 whr[3][KS];      // whh B-frags for my tile: 3 gates x KS k-steps
    short8 wxr[3][2];       // wih B-frags
    float bsr = 0.f, bsz = 0.f, binx = 0.f, bhnn = 0.f;
    if (act) {
#pragma unroll
        for (int g = 0; g < 3; ++g) {
#pragma unroll
            for (int ks = 0; ks < KS; ++ks)
                whr[g][ks] = *(const short8*)(whh + ((size_t)(g*KP + c))*KP + ks*32 + quad*8);
#pragma unroll
            for (int ks = 0; ks < 2; ++ks)
                wxr[g][ks] = *(const short8*)(wih + ((size_t)(g*KP + c))*64 + ks*32 + quad*8);
        }
        if (c < H) {
            bsr  = bih[c]       + bhh[c];
            bsz  = bih[H + c]   + bhh[H + c];
            binx = bih[2*H + c];
            bhnn = bhh[2*H + c];
        }
    }
    float hreg[4] = {0.f, 0.f, 0.f, 0.f};

    __syncthreads();

    int cur = 0;
    for (int t = 0; t < 512; ++t) {
        // ---- encoder layer 1 (VALU): 16 pts x 64 ch ----
        const float* pt = ptsb + (t & 1) * 64;
#pragma unroll
        for (int e = tid; e < 1024; e += 768) {
            int p = e >> 6, ch = e & 63;
            float v = w1s[ch*4+0]*pt[p*4+0] + w1s[ch*4+1]*pt[p*4+1]
                    + w1s[ch*4+2]*pt[p*4+2] + b1s[ch];
            h1s[p*72 + ch] = f2bf(elu_(v));
        }
        __syncthreads();                               // h1s ready

        // ---- pts store for t+1 + prefetch t+2 ----
        if (tid < 16) {
            float* dst = ptsb + ((t+1) & 1) * 64 + tid*4;
            dst[0] = px; dst[1] = py; dst[2] = pz;
            int tn = (t + 2 < 512) ? t + 2 : 511;
            int pn = idx[tn];
            px = myrow[3*pn + 0]; py = myrow[3*pn + 1]; pz = myrow[3*pn + 2];
        }

        // ---- encoder layer 2 (MFMA, waves 0..3) ----
        if (wave < 4) {
            f32x4 a2 = splat4(0.f);
#pragma unroll
            for (int ks = 0; ks < 2; ++ks) {
                short8 af = *(const short8*)(h1s + l16*72 + ks*32 + quad*8);
                short8 bf = *(const short8*)(w2s + (wave*16 + l16)*72 + ks*32 + quad*8);
                a2 = __builtin_amdgcn_mfma_f32_16x16x32_bf16(af, bf, a2, 0, 0, 0);
            }
            int c2 = wave*16 + l16;
            float b2v = b2s[c2];
#pragma unroll
            for (int j = 0; j < 4; ++j)
                xs[(quad*4 + j)*72 + c2] = f2bf(elu_(a2[j] + b2v));
        }
        __syncthreads();                               // xs ready

        const unsigned short* hc = hlds + cur * (16*HP8);
        unsigned short*       hn = hlds + (cur ^ 1) * (16*HP8);

        if (act) {
            f32x4 acc[4];                              // r, z, nx, nh
            acc[0] = splat4(bsr);
            acc[1] = splat4(bsz);
            acc[2] = splat4(binx);
            acc[3] = splat4(bhnn);
            // gx = x_t @ wih^T (K=64), B from registers
#pragma unroll
            for (int ks = 0; ks < 2; ++ks) {
                short8 xf = *(const short8*)(xs + l16*72 + ks*32 + quad*8);
#pragma unroll
                for (int g = 0; g < 3; ++g)
                    acc[g] = __builtin_amdgcn_mfma_f32_16x16x32_bf16(xf, wxr[g][ks], acc[g], 0, 0, 0);
            }
            // gh = h @ whh^T (K=KP), B from registers
#pragma unroll
            for (int ks = 0; ks < KS; ++ks) {
                short8 ah = *(const short8*)(hc + l16*HP8 + ks*32 + quad*8);
#pragma unroll
                for (int g = 0; g < 3; ++g) {
                    int gi = (g == 2) ? 3 : g;
                    acc[gi] = __builtin_amdgcn_mfma_f32_16x16x32_bf16(ah, whr[g][ks], acc[gi], 0, 0, 0);
                }
            }
            // gates + h update
#pragma unroll
            for (int j = 0; j < 4; ++j) {
                int m = quad*4 + j;
                float r  = sig_(acc[0][j]);
                float zg = sig_(acc[1][j]);
                float nn = tanh_(acc[2][j] + r * acc[3][j]);
                float hv = nn + zg * (hreg[j] - nn);
                hreg[j] = hv;
                hn[m*HP8 + c] = f2bf(hv);
            }
        }
        cur ^= 1;
        __syncthreads();                               // hn visible; xs/h1s free
    }

    // ---- final h (exact fp32 from registers) ----
    if (act && c < H)
#pragma unroll
        for (int j = 0; j < 4; ++j) {
            int m = quad*4 + j;
            hout[(size_t)(b0 + m)*H + c] = hreg[j];
        }
}

__global__ __launch_bounds__(768, 3) void gru_kernel(
    const float* __restrict__ obs,
    const int* __restrict__ prox_idx, const int* __restrict__ dist_idx,
    const float* __restrict__ w1p, const float* __restrict__ b1p,
    const float* __restrict__ w2p, const float* __restrict__ b2p,
    const float* __restrict__ w1d, const float* __restrict__ b1d,
    const float* __restrict__ w2d, const float* __restrict__ b2d,
    const unsigned short* __restrict__ wihp, const unsigned short* __restrict__ whhp,
    const unsigned short* __restrict__ wihd, const unsigned short* __restrict__ whhd,
    const float* __restrict__ bihp, const float* __restrict__ bhhp,
    const float* __restrict__ bihd, const float* __restrict__ bhhd,
    float* __restrict__ hp, float* __restrict__ hd)
{
    __shared__ char smem[28672];
    if (blockIdx.x < 128)
        gru_body<187, 192>(blockIdx.x, obs, prox_idx, w1p, b1p, w2p, b2p,
                           wihp, whhp, bihp, bhhp, hp, smem);
    else
        gru_body<64, 64>(blockIdx.x - 128, obs, dist_idx, w1d, b1d, w2d, b2d,
                         wihd, whhd, bihd, bhhd, hd, smem);
}

// ---------------------------------------------------------------------------
// mem GRU with T=1 and h0=0: f = (1-z)*n, gh == bhh.  fp32 exact.
// ---------------------------------------------------------------------------
__global__ __launch_bounds__(192) void mem_kernel(
    const float* __restrict__ hp, const float* __restrict__ hd,
    const float* __restrict__ mwp, const float* __restrict__ mbip, const float* __restrict__ mbhp,
    const float* __restrict__ mwd, const float* __restrict__ mbid, const float* __restrict__ mbhd,
    float* __restrict__ fp, float* __restrict__ fd)
{
    const int b = blockIdx.x, z = blockIdx.y;
    const float* h  = z ? hd  : hp;
    const float* W  = z ? mwd : mwp;
    const float* bi = z ? mbid : mbip;
    const float* bh = z ? mbhd : mbhp;
    float* out = z ? fd : fp;
    const int Hh = z ? 64 : 187;
    __shared__ float hrow[192];
    int j = threadIdx.x;
    if (j < Hh) hrow[j] = h[(size_t)b*Hh + j];
    __syncthreads();
    if (j < Hh) {
        float dr = 0.f, dz = 0.f, dn = 0.f;
        for (int k = 0; k < Hh; ++k) {
            float a = hrow[k];
            dr += a * W[(size_t)(0*Hh + j)*Hh + k];
            dz += a * W[(size_t)(1*Hh + j)*Hh + k];
            dn += a * W[(size_t)(2*Hh + j)*Hh + k];
        }
        float r  = sig_(dr + bi[j] + bh[j]);
        float zg = sig_(dz + bi[Hh + j] + bh[Hh + j]);
        float nn = tanh_(dn + bi[2*Hh + j] + r * bh[2*Hh + j]);
        out[(size_t)b*Hh + j] = (1.f - zg) * nn;
    }
}

__global__ void concat_kernel(const float* __restrict__ obs, const float* __restrict__ fp,
                              const float* __restrict__ fd, float* __restrict__ x0)
{
    int i = blockIdx.x * 256 + threadIdx.x;
    if (i >= 2048 * 299) return;
    int b = i / 299, k = i - b * 299;
    float v;
    if (k < 48)       v = obs[(size_t)b*3120 + k];
    else if (k < 235) v = fp[(size_t)b*187 + (k - 48)];
    else              v = fd[(size_t)b*64 + (k - 235)];
    x0[i] = v;
}

// ---------------------------------------------------------------------------
// fp32 GEMM + bias (+ELU):  C[b][n] = act( A[b][:] . W[n][:] + bias[n] )
// ---------------------------------------------------------------------------
__global__ __launch_bounds__(256) void gemm_kernel(
    const float* __restrict__ A, const float* __restrict__ W, const float* __restrict__ bias,
    float* __restrict__ C, int N, int K, int act)
{
    __shared__ float As[16][68];
    __shared__ float Ws[16][68];
    const int tid = threadIdx.x;
    const int n0 = blockIdx.x * 64, b0 = blockIdx.y * 64;
    const int tx = tid & 15, ty = tid >> 4;
    float acc[4][4];
#pragma unroll
    for (int i = 0; i < 4; ++i)
#pragma unroll
        for (int j = 0; j < 4; ++j) acc[i][j] = 0.f;
    const int lrow = tid >> 2, lseg = (tid & 3) * 4;
    for (int k0 = 0; k0 < K; k0 += 16) {
#pragma unroll
        for (int i = 0; i < 4; ++i) {
            int k = k0 + lseg + i;
            As[lseg + i][lrow] = (k < K) ? A[(size_t)(b0 + lrow)*K + k] : 0.f;
            Ws[lseg + i][lrow] = (k < K && (n0 + lrow) < N) ? W[(size_t)(n0 + lrow)*K + k] : 0.f;
        }
        __syncthreads();
#pragma unroll
        for (int kk = 0; kk < 16; ++kk) {
            float a[4], w[4];
#pragma unroll
            for (int i = 0; i < 4; ++i) a[i] = As[kk][ty*4 + i];
#pragma unroll
            for (int i = 0; i < 4; ++i) w[i] = Ws[kk][tx*4 + i];
#pragma unroll
            for (int i = 0; i < 4; ++i)
#pragma unroll
                for (int j = 0; j < 4; ++j) acc[i][j] += a[i] * w[j];
        }
        __syncthreads();
    }
#pragma unroll
    for (int j = 0; j < 4; ++j) {
        int n = n0 + tx*4 + j;
        if (n >= N) continue;
        float bv = bias[n];
#pragma unroll
        for (int i = 0; i < 4; ++i) {
            int b = b0 + ty*4 + i;
            float v = acc[i][j] + bv;
            if (act) v = elu_(v);
            C[(size_t)b*N + n] = v;
        }
    }
}

// ---------------------------------------------------------------------------
extern "C" void kernel_launch(void* const* d_in, const int* in_sizes, int n_in,
                              void* d_out, int out_size, void* d_ws, size_t ws_size,
                              hipStream_t stream)
{
    (void)in_sizes; (void)n_in; (void)out_size; (void)ws_size;
    const float* obs        = (const float*)d_in[0];
    const int*   prox_idx   = (const int*)d_in[1];
    const int*   dist_idx   = (const int*)d_in[2];
    const float* pe_prox_w1 = (const float*)d_in[3];
    const float* pe_prox_b1 = (const float*)d_in[4];
    const float* pe_prox_w2 = (const float*)d_in[5];
    const float* pe_prox_b2 = (const float*)d_in[6];
    const float* pe_dist_w1 = (const float*)d_in[7];
    const float* pe_dist_b1 = (const float*)d_in[8];
    const float* pe_dist_w2 = (const float*)d_in[9];
    const float* pe_dist_b2 = (const float*)d_in[10];
    const float* gp_wih = (const float*)d_in[11];
    const float* gp_whh = (const float*)d_in[12];
    const float* gp_bih = (const float*)d_in[13];
    const float* gp_bhh = (const float*)d_in[14];
    const float* gd_wih = (const float*)d_in[15];
    const float* gd_whh = (const float*)d_in[16];
    const float* gd_bih = (const float*)d_in[17];
    const float* gd_bhh = (const float*)d_in[18];
    const float* mp_wih = (const float*)d_in[19];
    const float* mp_bih = (const float*)d_in[21];
    const float* mp_bhh = (const float*)d_in[22];
    const float* md_wih = (const float*)d_in[23];
    const float* md_bih = (const float*)d_in[25];
    const float* md_bhh = (const float*)d_in[26];
    const float* aw0 = (const float*)d_in[27]; const float* ab0 = (const float*)d_in[28];
    const float* aw1 = (const float*)d_in[29]; const float* ab1 = (const float*)d_in[30];
    const float* aw2 = (const float*)d_in[31]; const float* ab2 = (const float*)d_in[32];
    const float* aw3 = (const float*)d_in[33]; const float* ab3 = (const float*)d_in[34];
    const float* aw4 = (const float*)d_in[35]; const float* ab4 = (const float*)d_in[36];
    float* out = (float*)d_out;

    char* ws = (char*)d_ws;
    size_t off = 0;
    auto alloc = [&](size_t bytes) -> char* {
        char* p = ws + off;
        off = (off + bytes + 255) & ~(size_t)255;
        return p;
    };
    unsigned short* whh_p = (unsigned short*)alloc(576*192*2);
    unsigned short* wih_p = (unsigned short*)alloc(576*64*2);
    unsigned short* whh_d = (unsigned short*)alloc(192*64*2);
    unsigned short* wih_d = (unsigned short*)alloc(192*64*2);
    float* hp = (float*)alloc((size_t)2048*187*4);
    float* hd = (float*)alloc((size_t)2048*64*4);
    float* fp = (float*)alloc((size_t)2048*187*4);
    float* fd = (float*)alloc((size_t)2048*64*4);
    float* x0 = (float*)alloc((size_t)2048*299*4);
    float* a1 = (float*)alloc((size_t)2048*1024*4);
    float* a2 = (float*)alloc((size_t)2048*512*4);
    float* a3 = (float*)alloc((size_t)2048*256*4);
    float* a4 = (float*)alloc((size_t)2048*128*4);

    // --- weight packs (bf16, B-operand layouts) ---
    pack_kernel<<<(36864+255)/256,  256, 0, stream>>>(gp_wih, wih_p, 187, 192, 64, 64, 36864);
    pack_kernel<<<(110592+255)/256, 256, 0, stream>>>(gp_whh, whh_p, 187, 192, 187, 192, 110592);
    pack_kernel<<<(12288+255)/256,  256, 0, stream>>>(gd_wih, wih_d, 64, 64, 64, 64, 12288);
    pack_kernel<<<(12288+255)/256,  256, 0, stream>>>(gd_whh, whh_d, 64, 64, 64, 64, 12288);

    // --- fused encoder + GRU recurrence (128 prox + 128 dist blocks) ---
    gru_kernel<<<256, 768, 0, stream>>>(
        obs, prox_idx, dist_idx,
        pe_prox_w1, pe_prox_b1, pe_prox_w2, pe_prox_b2,
        pe_dist_w1, pe_dist_b1, pe_dist_w2, pe_dist_b2,
        wih_p, whh_p, wih_d, whh_d,
        gp_bih, gp_bhh, gd_bih, gd_bhh, hp, hd);

    // --- mem GRUs (T=1, h0=0) ---
    mem_kernel<<<dim3(2048, 2), 192, 0, stream>>>(
        hp, hd, mp_wih, mp_bih, mp_bhh, md_wih, md_bih, md_bhh, fp, fd);

    // --- concat [proprio | fp | fd] ---
    concat_kernel<<<(2048*299 + 255)/256, 256, 0, stream>>>(obs, fp, fd, x0);

    // --- actor MLP ---
    gemm_kernel<<<dim3(16, 32), 256, 0, stream>>>(x0, aw0, ab0, a1, 1024, 299, 1);
    gemm_kernel<<<dim3(8,  32), 256, 0, stream>>>(a1, aw1, ab1, a2, 512, 1024, 1);
    gemm_kernel<<<dim3(4,  32), 256, 0, stream>>>(a2, aw2, ab2, a3, 256, 512, 1);
    gemm_kernel<<<dim3(2,  32), 256, 0, stream>>>(a3, aw3, ab3, a4, 128, 256, 1);
    gemm_kernel<<<dim3(1,  32), 256, 0, stream>>>(a4, aw4, ab4, out, 12, 128, 0);
}

// Round 4
// 1104.726 us; speedup vs baseline: 155.9042x; 1.2733x over previous
//
#include <hip/hip_runtime.h>
#include <stdint.h>

typedef __attribute__((ext_vector_type(8))) short short8;
typedef __attribute__((ext_vector_type(4))) float f32x4;

#define DEV __device__ __forceinline__

#define L2E 1.4426950408889634f

DEV unsigned short f2bf(float f) {
    union { float f; uint32_t u; } v; v.f = f;
    return (unsigned short)((v.u + 0x7FFFu + ((v.u >> 16) & 1u)) >> 16);
}
DEV float sig_(float x) {
    return __builtin_amdgcn_rcpf(1.f + __builtin_amdgcn_exp2f(-L2E * x));
}
DEV float tanh_(float x) {
    return 1.f - 2.f * __builtin_amdgcn_rcpf(1.f + __builtin_amdgcn_exp2f(2.f * L2E * x));
}
DEV float elu_(float x) {
    return x > 0.f ? x : __builtin_amdgcn_exp2f(L2E * x) - 1.f;
}
DEV f32x4 splat4(float v) { f32x4 r; r[0]=v; r[1]=v; r[2]=v; r[3]=v; return r; }
// Opaque register pin: after this, the compiler cannot rematerialize the load
// that produced v — it must keep v live in VGPRs across the loop.
DEV void pin(short8& v) { asm volatile("" : "+v"(v)); }

// ---------------------------------------------------------------------------
// pack fp32 weights -> bf16 in MFMA B-operand layout [G*NG rows (n)][Kd cols (k)]
// ---------------------------------------------------------------------------
__global__ void pack_kernel(const float* __restrict__ src, unsigned short* __restrict__ dst,
                            int Hs, int NG, int Ks, int Kd, int total)
{
    int e = blockIdx.x * 256 + threadIdx.x;
    if (e >= total) return;
    int n = e / Kd, k = e - n * Kd;
    int g = n / NG, jj = n - g * NG;
    float v = (jj < Hs && k < Ks) ? src[((size_t)(g * Hs + jj)) * Ks + k] : 0.f;
    dst[e] = f2bf(v);
}

// ---------------------------------------------------------------------------
// Fused encoder + GRU, software-pipelined: ONE barrier per step.
// One block = 16 batch rows, 768 thr (12 waves), all 512 steps.
// Iter i: l1 computes h1s(step i) | l2 computes xs(step i-1) | GRU does step
// i-2. All intra-iter accesses hit disjoint (double-buffered) LDS regions, so
// a single end-of-iter __syncthreads suffices. Wave w owns gate-col tile w;
// its whh/wih B-frags are PINNED in VGPRs (96 regs) -> zero steady-state
// weight traffic. fp32 h carried in hreg; bf16 h ping-pongs in LDS.
// LDS (prox-max sizes, 33280 B):
//   0      hlds [2][16][200] bf16 (12800)   22016  w2s [64][72] bf16 (9216)
//   12800  xs   [2][16][72] bf16  (4608)    31232  pts [2][16][4] f32 (512)
//   17408  h1s  [2][16][72] bf16  (4608)    31744  w1s [64][4] f32 (1024)
//   32768  b1s[64] f32 ; 33024 b2s[64] f32
// ---------------------------------------------------------------------------
template<int H, int KP>
DEV void gru_body(int blk,
                  const float* __restrict__ obs, const int* __restrict__ idx,
                  const float* __restrict__ w1, const float* __restrict__ b1,
                  const float* __restrict__ w2, const float* __restrict__ b2,
                  const unsigned short* __restrict__ wih, const unsigned short* __restrict__ whh,
                  const float* __restrict__ bih, const float* __restrict__ bhh,
                  float* __restrict__ hout, char* smem)
{
    constexpr int NCT = KP / 16;            // col tiles (= active gru waves)
    constexpr int KS  = KP / 32;            // k-steps for gh
    constexpr int HP8 = KP + 8;             // padded h row (shorts)

    unsigned short* hlds = (unsigned short*)(smem);
    unsigned short* xs   = (unsigned short*)(smem + 12800);
    unsigned short* h1s  = (unsigned short*)(smem + 17408);
    unsigned short* w2s  = (unsigned short*)(smem + 22016);
    float* ptsb          = (float*)(smem + 31232);
    float* w1s           = (float*)(smem + 31744);
    float* b1s           = (float*)(smem + 32768);
    float* b2s           = (float*)(smem + 33024);

    const int tid  = threadIdx.x;
    const int wave = tid >> 6, lane = tid & 63, quad = lane >> 4, l16 = lane & 15;
    const int b0   = blk * 16;
    const int ct   = wave;
    const bool act = (ct < NCT);
    const int c    = ct * 16 + l16;

    // ---- one-time staging ----
    for (int e = tid; e < 2*16*HP8; e += 768) hlds[e] = 0;
    for (int e = tid; e < 4096; e += 768) { int n = e >> 6, k = e & 63; w2s[n*72 + k] = f2bf(w2[e]); }
    if (tid < 192) w1s[(tid/3)*4 + (tid - (tid/3)*3)] = w1[tid];
    if (tid < 64) { b1s[tid] = b1[tid]; b2s[tid] = b2[tid]; }

    const float* myrow = obs + (size_t)(b0 + (tid & 15)) * 3120 + 48;
    float px = 0.f, py = 0.f, pz = 0.f;
    if (tid < 16) {
        int p0 = idx[0];
        ptsb[tid*4 + 0] = myrow[3*p0 + 0];
        ptsb[tid*4 + 1] = myrow[3*p0 + 1];
        ptsb[tid*4 + 2] = myrow[3*p0 + 2];
        int p1 = idx[1];
        px = myrow[3*p1 + 0]; py = myrow[3*p1 + 1]; pz = myrow[3*p1 + 2];
    }

    // ---- register-resident (pinned) weight fragments ----
    short8 whr[3][KS];
    short8 wxr[3][2];
    float bsr = 0.f, bsz = 0.f, binx = 0.f, bhnn = 0.f;
    {
        const int cl = act ? c : l16;       // inactive waves load tile 0 (valid addr)
#pragma unroll
        for (int g = 0; g < 3; ++g) {
#pragma unroll
            for (int ks = 0; ks < KS; ++ks)
                whr[g][ks] = *(const short8*)(whh + ((size_t)(g*KP + cl))*KP + ks*32 + quad*8);
#pragma unroll
            for (int ks = 0; ks < 2; ++ks)
                wxr[g][ks] = *(const short8*)(wih + ((size_t)(g*KP + cl))*64 + ks*32 + quad*8);
        }
    }
#pragma unroll
    for (int g = 0; g < 3; ++g) {
#pragma unroll
        for (int ks = 0; ks < KS; ++ks) pin(whr[g][ks]);
#pragma unroll
        for (int ks = 0; ks < 2; ++ks)  pin(wxr[g][ks]);
    }
    if (act && c < H) {
        bsr  = bih[c]       + bhh[c];
        bsz  = bih[H + c]   + bhh[H + c];
        binx = bih[2*H + c];
        bhnn = bhh[2*H + c];
    }
    float hreg[4] = {0.f, 0.f, 0.f, 0.f};

    __syncthreads();

    int cur = 0;
    for (int i = 0; i < 514; ++i) {
        // ---- l1: encoder layer 1 for step i ----
        if (i < 512) {
            const float* pt = ptsb + (i & 1) * 64;
            unsigned short* h1w = h1s + (i & 1) * (16*72);
#pragma unroll
            for (int e = tid; e < 1024; e += 768) {
                int p = e >> 6, ch = e & 63;
                float v = w1s[ch*4+0]*pt[p*4+0] + w1s[ch*4+1]*pt[p*4+1]
                        + w1s[ch*4+2]*pt[p*4+2] + b1s[ch];
                h1w[p*72 + ch] = f2bf(elu_(v));
            }
            // pts for step i+1 -> LDS; prefetch step i+2 -> regs
            if (tid < 16) {
                float* dst = ptsb + ((i+1) & 1) * 64 + tid*4;
                dst[0] = px; dst[1] = py; dst[2] = pz;
                int tn = (i + 2 < 512) ? i + 2 : 511;
                int pn = idx[tn];
                px = myrow[3*pn + 0]; py = myrow[3*pn + 1]; pz = myrow[3*pn + 2];
            }
        }
        // ---- l2: encoder layer 2 for step i-1 (waves 0..3) ----
        if (i >= 1 && i < 513 && wave < 4) {
            const unsigned short* h1r = h1s + ((i-1) & 1) * (16*72);
            unsigned short*       xw  = xs  + ((i-1) & 1) * (16*72);
            f32x4 a2 = splat4(0.f);
#pragma unroll
            for (int ks = 0; ks < 2; ++ks) {
                short8 af = *(const short8*)(h1r + l16*72 + ks*32 + quad*8);
                short8 bf = *(const short8*)(w2s + (wave*16 + l16)*72 + ks*32 + quad*8);
                a2 = __builtin_amdgcn_mfma_f32_16x16x32_bf16(af, bf, a2, 0, 0, 0);
            }
            int c2 = wave*16 + l16;
            float b2v = b2s[c2];
#pragma unroll
            for (int j = 0; j < 4; ++j)
                xw[(quad*4 + j)*72 + c2] = f2bf(elu_(a2[j] + b2v));
        }
        // ---- GRU step t = i-2 ----
        if (i >= 2) {
            int t = i - 2;
            const unsigned short* xsr = xs + (t & 1) * (16*72);
            const unsigned short* hc  = hlds + cur * (16*HP8);
            unsigned short*       hn  = hlds + (cur ^ 1) * (16*HP8);
            if (act) {
                f32x4 acc[4];                          // r, z, nx, nh
                acc[0] = splat4(bsr);
                acc[1] = splat4(bsz);
                acc[2] = splat4(binx);
                acc[3] = splat4(bhnn);
#pragma unroll
                for (int ks = 0; ks < 2; ++ks) {
                    short8 xf = *(const short8*)(xsr + l16*72 + ks*32 + quad*8);
#pragma unroll
                    for (int g = 0; g < 3; ++g)
                        acc[g] = __builtin_amdgcn_mfma_f32_16x16x32_bf16(xf, wxr[g][ks], acc[g], 0, 0, 0);
                }
#pragma unroll
                for (int ks = 0; ks < KS; ++ks) {
                    short8 ah = *(const short8*)(hc + l16*HP8 + ks*32 + quad*8);
#pragma unroll
                    for (int g = 0; g < 3; ++g) {
                        int gi = (g == 2) ? 3 : g;
                        acc[gi] = __builtin_amdgcn_mfma_f32_16x16x32_bf16(ah, whr[g][ks], acc[gi], 0, 0, 0);
                    }
                }
#pragma unroll
                for (int j = 0; j < 4; ++j) {
                    int m = quad*4 + j;
                    float r  = sig_(acc[0][j]);
                    float zg = sig_(acc[1][j]);
                    float nn = tanh_(acc[2][j] + r * acc[3][j]);
                    float hv = nn + zg * (hreg[j] - nn);
                    hreg[j] = hv;
                    hn[m*HP8 + c] = f2bf(hv);
                }
            }
            cur ^= 1;
        }
        __syncthreads();
    }

    // ---- final h (exact fp32 from registers) ----
    if (act && c < H)
#pragma unroll
        for (int j = 0; j < 4; ++j) {
            int m = quad*4 + j;
            hout[(size_t)(b0 + m)*H + c] = hreg[j];
        }
}

__global__ __launch_bounds__(768, 3) void gru_kernel(
    const float* __restrict__ obs,
    const int* __restrict__ prox_idx, const int* __restrict__ dist_idx,
    const float* __restrict__ w1p, const float* __restrict__ b1p,
    const float* __restrict__ w2p, const float* __restrict__ b2p,
    const float* __restrict__ w1d, const float* __restrict__ b1d,
    const float* __restrict__ w2d, const float* __restrict__ b2d,
    const unsigned short* __restrict__ wihp, const unsigned short* __restrict__ whhp,
    const unsigned short* __restrict__ wihd, const unsigned short* __restrict__ whhd,
    const float* __restrict__ bihp, const float* __restrict__ bhhp,
    const float* __restrict__ bihd, const float* __restrict__ bhhd,
    float* __restrict__ hp, float* __restrict__ hd)
{
    __shared__ char smem[33280];
    if (blockIdx.x < 128)
        gru_body<187, 192>(blockIdx.x, obs, prox_idx, w1p, b1p, w2p, b2p,
                           wihp, whhp, bihp, bhhp, hp, smem);
    else
        gru_body<64, 64>(blockIdx.x - 128, obs, dist_idx, w1d, b1d, w2d, b2d,
                         wihd, whhd, bihd, bhhd, hd, smem);
}

// ---------------------------------------------------------------------------
// mem GRU gates (T=1, h0=0): f = (1-z)*n; G = h @ W^T precomputed by gemm.
// ---------------------------------------------------------------------------
__global__ void memgate_kernel(const float* __restrict__ Gp, const float* __restrict__ Gd,
                               const float* __restrict__ mbip, const float* __restrict__ mbhp,
                               const float* __restrict__ mbid, const float* __restrict__ mbhd,
                               float* __restrict__ fp, float* __restrict__ fd)
{
    int i = blockIdx.x * 256 + threadIdx.x;
    if (blockIdx.y == 0) {
        if (i >= 2048*187) return;
        int b = i / 187, j = i - b*187;
        float dr = Gp[(size_t)b*561 + j];
        float dz = Gp[(size_t)b*561 + 187 + j];
        float dn = Gp[(size_t)b*561 + 374 + j];
        float r  = sig_(dr + mbip[j] + mbhp[j]);
        float zg = sig_(dz + mbip[187+j] + mbhp[187+j]);
        float nn = tanh_(dn + mbip[374+j] + r * mbhp[374+j]);
        fp[i] = (1.f - zg) * nn;
    } else {
        if (i >= 2048*64) return;
        int b = i >> 6, j = i & 63;
        float dr = Gd[(size_t)b*192 + j];
        float dz = Gd[(size_t)b*192 + 64 + j];
        float dn = Gd[(size_t)b*192 + 128 + j];
        float r  = sig_(dr + mbid[j] + mbhd[j]);
        float zg = sig_(dz + mbid[64+j] + mbhd[64+j]);
        float nn = tanh_(dn + mbid[128+j] + r * mbhd[128+j]);
        fd[i] = (1.f - zg) * nn;
    }
}

__global__ void concat_kernel(const float* __restrict__ obs, const float* __restrict__ fp,
                              const float* __restrict__ fd, float* __restrict__ x0)
{
    int i = blockIdx.x * 256 + threadIdx.x;
    if (i >= 2048 * 299) return;
    int b = i / 299, k = i - b * 299;
    float v;
    if (k < 48)       v = obs[(size_t)b*3120 + k];
    else if (k < 235) v = fp[(size_t)b*187 + (k - 48)];
    else              v = fd[(size_t)b*64 + (k - 235)];
    x0[i] = v;
}

// ---------------------------------------------------------------------------
// fp32 GEMM + bias (+ELU):  C[b][n] = act( A[b][:] . W[n][:] + bias[n] )
// 64x64 tile, 256 thr, 4x4 micro-tile, float4 LDS reads. bias may be null.
// ---------------------------------------------------------------------------
__global__ __launch_bounds__(256) void gemm_kernel(
    const float* __restrict__ A, const float* __restrict__ W, const float* __restrict__ bias,
    float* __restrict__ C, int N, int K, int act)
{
    __shared__ float As[16][68];
    __shared__ float Ws[16][68];
    const int tid = threadIdx.x;
    const int n0 = blockIdx.x * 64, b0 = blockIdx.y * 64;
    const int tx = tid & 15, ty = tid >> 4;
    float acc[4][4];
#pragma unroll
    for (int i = 0; i < 4; ++i)
#pragma unroll
        for (int j = 0; j < 4; ++j) acc[i][j] = 0.f;
    const int lrow = tid >> 2, lseg = (tid & 3) * 4;
    for (int k0 = 0; k0 < K; k0 += 16) {
#pragma unroll
        for (int i = 0; i < 4; ++i) {
            int k = k0 + lseg + i;
            As[lseg + i][lrow] = (k < K) ? A[(size_t)(b0 + lrow)*K + k] : 0.f;
            Ws[lseg + i][lrow] = (k < K && (n0 + lrow) < N) ? W[(size_t)(n0 + lrow)*K + k] : 0.f;
        }
        __syncthreads();
#pragma unroll
        for (int kk = 0; kk < 16; ++kk) {
            f32x4 av = *(const f32x4*)(&As[kk][ty*4]);
            f32x4 wv = *(const f32x4*)(&Ws[kk][tx*4]);
#pragma unroll
            for (int i = 0; i < 4; ++i)
#pragma unroll
                for (int j = 0; j < 4; ++j) acc[i][j] += av[i] * wv[j];
        }
        __syncthreads();
    }
#pragma unroll
    for (int j = 0; j < 4; ++j) {
        int n = n0 + tx*4 + j;
        if (n >= N) continue;
        float bv = bias ? bias[n] : 0.f;
#pragma unroll
        for (int i = 0; i < 4; ++i) {
            int b = b0 + ty*4 + i;
            float v = acc[i][j] + bv;
            if (act) v = elu_(v);
            C[(size_t)b*N + n] = v;
        }
    }
}

// ---------------------------------------------------------------------------
extern "C" void kernel_launch(void* const* d_in, const int* in_sizes, int n_in,
                              void* d_out, int out_size, void* d_ws, size_t ws_size,
                              hipStream_t stream)
{
    (void)in_sizes; (void)n_in; (void)out_size; (void)ws_size;
    const float* obs        = (const float*)d_in[0];
    const int*   prox_idx   = (const int*)d_in[1];
    const int*   dist_idx   = (const int*)d_in[2];
    const float* pe_prox_w1 = (const float*)d_in[3];
    const float* pe_prox_b1 = (const float*)d_in[4];
    const float* pe_prox_w2 = (const float*)d_in[5];
    const float* pe_prox_b2 = (const float*)d_in[6];
    const float* pe_dist_w1 = (const float*)d_in[7];
    const float* pe_dist_b1 = (const float*)d_in[8];
    const float* pe_dist_w2 = (const float*)d_in[9];
    const float* pe_dist_b2 = (const float*)d_in[10];
    const float* gp_wih = (const float*)d_in[11];
    const float* gp_whh = (const float*)d_in[12];
    const float* gp_bih = (const float*)d_in[13];
    const float* gp_bhh = (const float*)d_in[14];
    const float* gd_wih = (const float*)d_in[15];
    const float* gd_whh = (const float*)d_in[16];
    const float* gd_bih = (const float*)d_in[17];
    const float* gd_bhh = (const float*)d_in[18];
    const float* mp_wih = (const float*)d_in[19];
    const float* mp_bih = (const float*)d_in[21];
    const float* mp_bhh = (const float*)d_in[22];
    const float* md_wih = (const float*)d_in[23];
    const float* md_bih = (const float*)d_in[25];
    const float* md_bhh = (const float*)d_in[26];
    const float* aw0 = (const float*)d_in[27]; const float* ab0 = (const float*)d_in[28];
    const float* aw1 = (const float*)d_in[29]; const float* ab1 = (const float*)d_in[30];
    const float* aw2 = (const float*)d_in[31]; const float* ab2 = (const float*)d_in[32];
    const float* aw3 = (const float*)d_in[33]; const float* ab3 = (const float*)d_in[34];
    const float* aw4 = (const float*)d_in[35]; const float* ab4 = (const float*)d_in[36];
    float* out = (float*)d_out;

    char* ws = (char*)d_ws;
    size_t off = 0;
    auto alloc = [&](size_t bytes) -> char* {
        char* p = ws + off;
        off = (off + bytes + 255) & ~(size_t)255;
        return p;
    };
    unsigned short* whh_p = (unsigned short*)alloc(576*192*2);
    unsigned short* wih_p = (unsigned short*)alloc(576*64*2);
    unsigned short* whh_d = (unsigned short*)alloc(192*64*2);
    unsigned short* wih_d = (unsigned short*)alloc(192*64*2);
    float* hp = (float*)alloc((size_t)2048*187*4);
    float* hd = (float*)alloc((size_t)2048*64*4);
    float* fp = (float*)alloc((size_t)2048*187*4);
    float* fd = (float*)alloc((size_t)2048*64*4);
    float* x0 = (float*)alloc((size_t)2048*299*4);
    float* a1 = (float*)alloc((size_t)2048*1024*4);
    float* a2 = (float*)alloc((size_t)2048*512*4);
    float* a3 = (float*)alloc((size_t)2048*256*4);
    float* a4 = (float*)alloc((size_t)2048*128*4);
    // mem-GRU gemm outputs alias a1 (consumed by memgate before gemm0 writes a1)
    float* Gp = a1;                       // [2048,561]
    float* Gd = a1 + (size_t)2048*561;    // [2048,192]

    // --- weight packs (bf16, B-operand layouts) ---
    pack_kernel<<<(36864+255)/256,  256, 0, stream>>>(gp_wih, wih_p, 187, 192, 64, 64, 36864);
    pack_kernel<<<(110592+255)/256, 256, 0, stream>>>(gp_whh, whh_p, 187, 192, 187, 192, 110592);
    pack_kernel<<<(12288+255)/256,  256, 0, stream>>>(gd_wih, wih_d, 64, 64, 64, 64, 12288);
    pack_kernel<<<(12288+255)/256,  256, 0, stream>>>(gd_whh, whh_d, 64, 64, 64, 64, 12288);

    // --- fused encoder + GRU recurrence (128 prox + 128 dist blocks) ---
    gru_kernel<<<256, 768, 0, stream>>>(
        obs, prox_idx, dist_idx,
        pe_prox_w1, pe_prox_b1, pe_prox_w2, pe_prox_b2,
        pe_dist_w1, pe_dist_b1, pe_dist_w2, pe_dist_b2,
        wih_p, whh_p, wih_d, whh_d,
        gp_bih, gp_bhh, gd_bih, gd_bhh, hp, hd);

    // --- mem GRUs as gemm + gates ---
    gemm_kernel<<<dim3(9, 32), 256, 0, stream>>>(hp, mp_wih, nullptr, Gp, 561, 187, 0);
    gemm_kernel<<<dim3(3, 32), 256, 0, stream>>>(hd, md_wih, nullptr, Gd, 192, 64, 0);
    memgate_kernel<<<dim3(1496, 2), 256, 0, stream>>>(Gp, Gd, mp_bih, mp_bhh, md_bih, md_bhh, fp, fd);

    // --- concat [proprio | fp | fd] ---
    concat_kernel<<<(2048*299 + 255)/256, 256, 0, stream>>>(obs, fp, fd, x0);

    // --- actor MLP ---
    gemm_kernel<<<dim3(16, 32), 256, 0, stream>>>(x0, aw0, ab0, a1, 1024, 299, 1);
    gemm_kernel<<<dim3(8,  32), 256, 0, stream>>>(a1, aw1, ab1, a2, 512, 1024, 1);
    gemm_kernel<<<dim3(4,  32), 256, 0, stream>>>(a2, aw2, ab2, a3, 256, 512, 1);
    gemm_kernel<<<dim3(2,  32), 256, 0, stream>>>(a3, aw3, ab3, a4, 128, 256, 1);
    gemm_kernel<<<dim3(1,  32), 256, 0, stream>>>(a4, aw4, ab4, out, 12, 128, 0);
}